// Round 1
// 342.959 us; speedup vs baseline: 1.0631x; 1.0631x over previous
//
#include <hip/hip_runtime.h>
#include <hip/hip_fp16.h>

// Persistent 256-block kernel (1 block/CU forced by ~150 KB LDS).
// Rows 2b,2b+1 of all 64 Omega_t cached ONCE in LDS as fp16 (validated
// R4-R8, absmax 0.0078). NTAY=3 Taylor terms of expm(A)@v.
//
// Exchange (fence-free, R7): relaxed agent-scope 8-byte atomics only.
// R9: TWO floats per word, tag embedded in low-2 mantissa bits of float0
// (one atom -> no ordering needed; perturbation <=3*2^-23 rel). 256 words
// per round, one per 64 B line, 4 rotating buffers (64 KB of d_ws,
// re-poisoned 0xAA each launch; poison low2=2 != tag 0 of rounds 0..3;
// skew induction: publish r+1 strictly after full gather of r -> distance-4
// buffer reuse and period-16 tag reuse are safe).
// W2/W3 in registers; gum/b2/b3 in LDS.
// R10: grid-stride gum_s load (fixed NaN from uninit LDS at steps >= 8).
// R11 (this round): latency-bound, not BW/compute-bound (VALU 11%, HBM 2%).
//  - Taylor rounds are now WAVE0-SOLO and barrier-free: wave0 lane l keeps
//    vector elems 8l..8l+7 in registers (= its 4 exchange words), dot is
//    16 reg-fmas from A0_s/A1_s float4 reads + one interleaved butterfly,
//    lane0 publishes immediately. Removes ~6 barriers + two 2-level
//    reductions + w_s LDS round-trips per step from the critical chain.
//  - h1 round: bias + tgt-half dot precomputed (cB_s), W1-top column slice
//    in wave0 regs -> publish ~50 cy after the vnew gather (kills the
//    per-step global b1[b] load on the critical path).
//  - done-argmax: single wave0 butterfly (was 3-barrier two-level).
//  - Omega staging float4-vectorized (4x fewer latency batches).
//  Exchange protocol/tags/rotation IDENTICAL to R9/R10 (publish-after-
//  full-gather induction preserved: wave0 itself full-gathers each Taylor
//  round; h1 is fully gathered before the A-mix barrier that precedes the
//  next publish).

#define NBLK 256
#define NTHR 512
#define NSTEP 20
#define NTAY 3
#define RBUF 4

typedef unsigned long long ull;

// word i (i<256) of buffer buf: 64 B apart (X is ull*, offset in ull units)
#define XW(buf, i) (X + ((((buf) << 8) + (i)) << 3))

__device__ __forceinline__ float wredsum(float p) {
#pragma unroll
  for (int off = 32; off > 0; off >>= 1) p += __shfl_xor(p, off, 64);
  return p;
}

__device__ __forceinline__ void wredsum2(float& p0, float& p1) {
#pragma unroll
  for (int off = 32; off > 0; off >>= 1) {
    float t0 = __shfl_xor(p0, off, 64);
    float t1 = __shfl_xor(p1, off, 64);
    p0 += t0;
    p1 += t1;
  }
}

__device__ __forceinline__ void publish2(ull* w, float v0, float v1, unsigned int tag2) {
  unsigned int u0 = (__float_as_uint(v0) & ~3u) | tag2;
  ull x = (ull)u0 | ((ull)__float_as_uint(v1) << 32);
  __hip_atomic_store(w, x, __ATOMIC_RELAXED, __HIP_MEMORY_SCOPE_AGENT);
}

__device__ __forceinline__ float2 poll2(ull* w, unsigned int tag2) {
  int it = 0;
  for (;;) {
    ull x = __hip_atomic_load(w, __ATOMIC_RELAXED, __HIP_MEMORY_SCOPE_AGENT);
    if ((unsigned int)(x & 3u) == tag2) {
      float2 r;
      r.x = __uint_as_float((unsigned int)x);
      r.y = __uint_as_float((unsigned int)(x >> 32));
      return r;
    }
    if (it == 0)      __builtin_amdgcn_s_sleep(1);
    else if (it == 1) __builtin_amdgcn_s_sleep(2);
    else              __builtin_amdgcn_s_sleep(4);
    if (it < 2) ++it;
  }
}

// lane-quad poll: 4 words (64 B apart) -> 8 floats; all 4 loads kept in
// flight per retry iteration (hand-unrolled, no runtime-indexed arrays).
__device__ __forceinline__ void poll8(ull* w0, unsigned int tg, float* o) {
  ull x0 = 0, x1 = 0, x2 = 0, x3 = 0;
  bool g0 = false, g1 = false, g2 = false, g3 = false;
  int it = 0;
  for (;;) {
    if (!g0) { ull x = __hip_atomic_load(w0,      __ATOMIC_RELAXED, __HIP_MEMORY_SCOPE_AGENT); if ((unsigned int)(x & 3u) == tg) { x0 = x; g0 = true; } }
    if (!g1) { ull x = __hip_atomic_load(w0 + 8,  __ATOMIC_RELAXED, __HIP_MEMORY_SCOPE_AGENT); if ((unsigned int)(x & 3u) == tg) { x1 = x; g1 = true; } }
    if (!g2) { ull x = __hip_atomic_load(w0 + 16, __ATOMIC_RELAXED, __HIP_MEMORY_SCOPE_AGENT); if ((unsigned int)(x & 3u) == tg) { x2 = x; g2 = true; } }
    if (!g3) { ull x = __hip_atomic_load(w0 + 24, __ATOMIC_RELAXED, __HIP_MEMORY_SCOPE_AGENT); if ((unsigned int)(x & 3u) == tg) { x3 = x; g3 = true; } }
    if (g0 && g1 && g2 && g3) break;
    if (it == 0)      __builtin_amdgcn_s_sleep(1);
    else if (it == 1) __builtin_amdgcn_s_sleep(2);
    else              __builtin_amdgcn_s_sleep(4);
    if (it < 2) ++it;
  }
  o[0] = __uint_as_float((unsigned int)x0); o[1] = __uint_as_float((unsigned int)(x0 >> 32));
  o[2] = __uint_as_float((unsigned int)x1); o[3] = __uint_as_float((unsigned int)(x1 >> 32));
  o[4] = __uint_as_float((unsigned int)x2); o[5] = __uint_as_float((unsigned int)(x2 >> 32));
  o[6] = __uint_as_float((unsigned int)x3); o[7] = __uint_as_float((unsigned int)(x3 >> 32));
}

__global__ __launch_bounds__(NTHR) void petri_kernel(
    const float* __restrict__ vsrc, const float* __restrict__ vtgt,
    const float* __restrict__ omg,  const float* __restrict__ W1,
    const float* __restrict__ b1,   const float* __restrict__ W2,
    const float* __restrict__ b2,   const float* __restrict__ W3,
    const float* __restrict__ b3,   const float* __restrict__ gum,
    ull* __restrict__ X, float* __restrict__ out) {
  __shared__ __half2 oh[64 * 512];   // 128 KB: {row2b[j], row2b+1[j]} per t
  __shared__ __align__(16) float A0_s[512];
  __shared__ __align__(16) float A1_s[512];
  __shared__ __align__(16) float v_loc[512];
  __shared__ float tgt_s[512];
  __shared__ float w1c_s[1024];      // W1 column b (both halves)
  __shared__ float gum_s[NSTEP * 64];
  __shared__ float b2_s[128], b3_s[64];
  __shared__ float soft_s[64], h1_s[256], h2_s[128];
  __shared__ float redp[512];
  __shared__ float rf8[8];
  __shared__ int   ri8[8];
  __shared__ float cB_s[1];
  __shared__ int   bc[1];

  const int b = blockIdx.x, tid = threadIdx.x;
  const int wv = tid >> 6, ln = tid & 63;

  v_loc[tid] = vsrc[tid];
  tgt_s[tid] = vtgt[tid];
  w1c_s[tid] = W1[tid * 256 + b];
  w1c_s[tid + 512] = W1[(tid + 512) * 256 + b];
  for (int i = tid; i < NSTEP * 64; i += NTHR) gum_s[i] = gum[i];  // R10 fix
  if (tid >= NTHR - 128) {
    int j = tid - (NTHR - 128);
    b2_s[j] = b2[j];
    if (j < 64) b3_s[j] = b3[j];
  }
  // W2 column slice in registers: thread (o=tid&127,q=tid>>7) holds
  // W2[(q*64+i)*128+o], i=0..63
  float w2r[64];
  {
    const int o = tid & 127, q = tid >> 7;
    const float* p = W2 + ((q << 6) * 128) + o;
#pragma unroll
    for (int i = 0; i < 64; ++i) w2r[i] = p[i * 128];
  }
  // W3 slice: thread (o=tid&63,q=tid>>6) holds W3[(q*16+i)*64+o], i=0..15
  float w3r[16];
  {
    const int o = tid & 63, q = tid >> 6;
    const float* p = W3 + ((q << 4) * 64) + o;
#pragma unroll
    for (int i = 0; i < 16; ++i) w3r[i] = p[i * 64];
  }
  // Omega rows 2b,2b+1 -> LDS fp16, float4-vectorized (R11)
  {
    const int tq = tid >> 7;            // 0..3 : t within group of 4
    const int c4 = (tid & 127) << 2;    // col 0..508 step 4
    const float* rp = omg + (b << 10) + c4;
#pragma unroll 4
    for (int g = 0; g < 16; ++g) {
      const int t = (g << 2) + tq;
      const float* p = rp + t * 262144;
      const float4 f0 = *(const float4*)(p);        // row 2b
      const float4 f1 = *(const float4*)(p + 512);  // row 2b+1
      __half2* dst = oh + t * 512 + c4;
      dst[0] = __floats2half2_rn(f0.x, f1.x);
      dst[1] = __floats2half2_rn(f0.y, f1.y);
      dst[2] = __floats2half2_rn(f0.z, f1.z);
      dst[3] = __floats2half2_rn(f0.w, f1.w);
    }
  }
  __syncthreads();

  // cB = b1[b] + dot(tgt, W1_bot[:,b])  -- hoists bias+tgt half off the
  // per-step critical path (R11)
  {
    float p = tgt_s[tid] * w1c_s[tid + 512];
    p = wredsum(p);
    if (ln == 0) rf8[wv] = p;
    __syncthreads();
    if (tid == 0) {
      float a = b1[b];
      for (int q = 0; q < 8; ++q) a += rf8[q];
      cB_s[0] = a;
    }
    __syncthreads();
  }

  // target argmax (identical in every block), first-index tie-break
  int tgtIdx;
  {
    float v = tgt_s[tid]; int ix = tid;
#pragma unroll
    for (int off = 32; off > 0; off >>= 1) {
      float ov = __shfl_xor(v, off, 64); int oi = __shfl_xor(ix, off, 64);
      if (ov > v || (ov == v && oi < ix)) { v = ov; ix = oi; }
    }
    if (ln == 0) { rf8[wv] = v; ri8[wv] = ix; }
    __syncthreads();
    if (tid == 0) {
      float bv = rf8[0]; int bix = ri8[0];
      for (int q = 1; q < 8; ++q)
        if (rf8[q] > bv || (rf8[q] == bv && ri8[q] < bix)) { bv = rf8[q]; bix = ri8[q]; }
      bc[0] = bix;
    }
    __syncthreads();
    tgtIdx = bc[0];
    __syncthreads();
  }

  // wave0 register state: lane l owns vector elems 8l..8l+7 (= exchange
  // words 4l..4l+3) and the matching W1-top column-slice.
  float vreg[8], w1t[8];
  if (wv == 0) {
    const int l8 = ln << 3;
#pragma unroll
    for (int k = 0; k < 8; ++k) { vreg[k] = v_loc[l8 + k]; w1t[k] = w1c_s[l8 + k]; }
  }

  int d = 0;
  int r = 0;  // global round counter (uniform across blocks)

  for (int s = 0; s < NSTEP; ++s) {
    if (d) {  // frozen: zero logits row; no exchanges (uniform across blocks)
      if (b == 0 && tid < 64) out[512 + s * 64 + tid] = 0.0f;
      continue;
    }

    // ---- round r: h1[b] = relu(dot(v, W1_top[:,b]) + cB) ----
    {
      const int buf = r & (RBUF - 1);
      const unsigned int tg = (unsigned int)((r >> 2) & 3);
      if (wv == 0) {
        float p = 0.f;
#pragma unroll
        for (int k = 0; k < 8; ++k) p = fmaf(vreg[k], w1t[k], p);
        p = wredsum(p);
        if (ln == 0) {
          float h = fmaxf(p + cB_s[0], 0.f);
          publish2(XW(buf, b), h, h, tg);
        }
      }
      if (tid < 256) h1_s[tid] = poll2(XW(buf, tid), tg).x;
      __syncthreads();
      ++r;
    }

    // ---- replicated L2/L3/softmax (register weights) ----
    {
      const int q = tid >> 7;
      float a = 0.f;
      const float* hp = h1_s + (q << 6);
#pragma unroll
      for (int i = 0; i < 64; ++i) a = fmaf(hp[i], w2r[i], a);
      redp[tid] = a;
    }
    __syncthreads();
    if (tid < 128) {
      float rr = redp[tid] + redp[tid + 128] + redp[tid + 256] + redp[tid + 384] + b2_s[tid];
      h2_s[tid] = fmaxf(rr, 0.f);
    }
    __syncthreads();
    {
      const int q = tid >> 6;
      float a = 0.f;
      const float* hp = h2_s + (q << 4);
#pragma unroll
      for (int i = 0; i < 16; ++i) a = fmaf(hp[i], w3r[i], a);
      redp[tid] = a;
    }
    __syncthreads();
    if (tid < 64) {
      float a = b3_s[tid];
#pragma unroll
      for (int q = 0; q < 8; ++q) a += redp[tid + (q << 6)];
      float lg = a + gum_s[s * 64 + tid];  // TAU = 1
      float mx = lg;
#pragma unroll
      for (int off = 32; off > 0; off >>= 1) mx = fmaxf(mx, __shfl_xor(mx, off, 64));
      float e = __expf(lg - mx);
      float sm = e;
#pragma unroll
      for (int off = 32; off > 0; off >>= 1) sm += __shfl_xor(sm, off, 64);
      soft_s[tid] = e / sm;
      if (b == 0) out[512 + s * 64 + tid] = a;  // pre-gumbel logits
    }
    __syncthreads();

    // ---- mix 2 rows of A from LDS fp16 ----
    {
      float a0 = 0.f, a1 = 0.f;
#pragma unroll 8
      for (int t = 0; t < 64; ++t) {
        float2 xy = __half22float2(oh[t * 512 + tid]);
        float sv = soft_s[t];
        a0 = fmaf(sv, xy.x, a0);
        a1 = fmaf(sv, xy.y, a1);
      }
      A0_s[tid] = a0; A1_s[tid] = a1;
    }
    __syncthreads();

    // ---- rounds r..r+2: Taylor n=1..NTAY, WAVE0 SOLO (R11) ----
    // No barriers, no LDS round-trips: dot from A0_s/A1_s float4 + regs,
    // one interleaved butterfly, lane0 publishes; lane-quad gather -> regs.
    if (wv == 0) {
      const int l8 = ln << 3;
      float wreg[8];
#pragma unroll
      for (int k = 0; k < 8; ++k) wreg[k] = vreg[k];
      float acc0 = 0.f, acc1 = 0.f;
#pragma unroll
      for (int n = 1; n <= NTAY; ++n) {
        const int rr = r + (n - 1);
        const int buf = rr & (RBUF - 1);
        const unsigned int tg = (unsigned int)((rr >> 2) & 3);
        const float4 a00 = *(const float4*)(A0_s + l8);
        const float4 a01 = *(const float4*)(A0_s + l8 + 4);
        const float4 a10 = *(const float4*)(A1_s + l8);
        const float4 a11 = *(const float4*)(A1_s + l8 + 4);
        float p0 = 0.f, p1 = 0.f;
        p0 = fmaf(a00.x, wreg[0], p0); p0 = fmaf(a00.y, wreg[1], p0);
        p0 = fmaf(a00.z, wreg[2], p0); p0 = fmaf(a00.w, wreg[3], p0);
        p0 = fmaf(a01.x, wreg[4], p0); p0 = fmaf(a01.y, wreg[5], p0);
        p0 = fmaf(a01.z, wreg[6], p0); p0 = fmaf(a01.w, wreg[7], p0);
        p1 = fmaf(a10.x, wreg[0], p1); p1 = fmaf(a10.y, wreg[1], p1);
        p1 = fmaf(a10.z, wreg[2], p1); p1 = fmaf(a10.w, wreg[3], p1);
        p1 = fmaf(a11.x, wreg[4], p1); p1 = fmaf(a11.y, wreg[5], p1);
        p1 = fmaf(a11.z, wreg[6], p1); p1 = fmaf(a11.w, wreg[7], p1);
        wredsum2(p0, p1);
        if (ln == 0) {
          float s0, s1;
          if (n == 1) {
            s0 = p0; s1 = p1;
            acc0 = v_loc[(b << 1)] + s0;
            acc1 = v_loc[(b << 1) + 1] + s1;
          } else {
            const float inv = (n == 2) ? 0.5f : (1.0f / 3.0f);
            s0 = p0 * inv; s1 = p1 * inv;
            acc0 += s0; acc1 += s1;
          }
          const float q0 = (n < NTAY) ? s0 : acc0;  // last round publishes vnew
          const float q1 = (n < NTAY) ? s1 : acc1;
          publish2(XW(buf, b), q0, q1, tg);
        }
        poll8(XW(buf, (ln << 2)), tg, wreg);
      }
      // vnew -> regs + LDS; solo argmax; done flag
#pragma unroll
      for (int k = 0; k < 8; ++k) vreg[k] = wreg[k];
      *(float4*)(v_loc + l8)     = make_float4(wreg[0], wreg[1], wreg[2], wreg[3]);
      *(float4*)(v_loc + l8 + 4) = make_float4(wreg[4], wreg[5], wreg[6], wreg[7]);
      float mv = wreg[0]; int mi = l8;
#pragma unroll
      for (int k = 1; k < 8; ++k) if (wreg[k] > mv) { mv = wreg[k]; mi = l8 + k; }
#pragma unroll
      for (int off = 32; off > 0; off >>= 1) {
        float ov = __shfl_xor(mv, off, 64); int oi = __shfl_xor(mi, off, 64);
        if (ov > mv || (ov == mv && oi < mi)) { mv = ov; mi = oi; }
      }
      if (ln == 0) bc[0] = (mi == tgtIdx) ? 1 : 0;
    }
    __syncthreads();
    if (bc[0]) d = 1;
    r += NTAY;
  }

  // ---- epilogue: v_loc holds v_final ----
  if (b == 0) out[tid] = v_loc[tid];
}

extern "C" void kernel_launch(void* const* d_in, const int* in_sizes, int n_in,
                              void* d_out, int out_size, void* d_ws, size_t ws_size,
                              hipStream_t stream) {
  (void)in_sizes; (void)n_in; (void)out_size; (void)ws_size;
  petri_kernel<<<dim3(NBLK), dim3(NTHR), 0, stream>>>(
      (const float*)d_in[0], (const float*)d_in[1], (const float*)d_in[2],
      (const float*)d_in[3], (const float*)d_in[4], (const float*)d_in[5],
      (const float*)d_in[6], (const float*)d_in[7], (const float*)d_in[8],
      (const float*)d_in[9], (ull*)d_ws, (float*)d_out);
}